// Round 1
// baseline (56.680 us; speedup 1.0000x reference)
//
#include <hip/hip_runtime.h>

// MakeCutouts: 32 random crops (size in [224,512]) of a [2,3,512,512] fp32
// image, each adaptive-avg-pooled (PyTorch semantics) to 224x224.
// Output: [32*2, 3, 224, 224] fp32.
//
// Direct per-output-pixel formulation: bin (i,j) of cutout n averages input
// rows [oy + floor(i*sz/224), oy + ceil((i+1)*sz/224)) and cols likewise.
// Bin spans <= 3x3 input pixels (sz <= 512 => sz/224 < 2.29).

constexpr int CUT = 224;
constexpr int BC  = 6;        // B*C = 2*3
constexpr int HH  = 512;
constexpr int WW  = 512;
constexpr int PIX = CUT * CUT;   // 50176 = 196 * 256

__global__ __launch_bounds__(256) void make_cutouts_kernel(
    const float* __restrict__ in,     // [B, C, H, W]
    const int*   __restrict__ sizes,  // [32]
    const int*   __restrict__ offx,   // [32]
    const int*   __restrict__ offy,   // [32]
    float*       __restrict__ out)    // [32*B, C, 224, 224]
{
    const int p   = blockIdx.x * 256 + threadIdx.x;  // pixel index in 224x224
    const int img = blockIdx.y;                      // n*6 + b*3 + c  (uniform)
    const int n   = img / BC;                        // scalar (SALU) math
    const int bc  = img - n * BC;                    // b*3 + c == input plane

    const int i = p / CUT;
    const int j = p - i * CUT;

    const int sz = sizes[n];
    const int oy = offy[n];
    const int ox = offx[n];

    const int sy = oy + (i * sz) / CUT;
    const int ey = oy + ((i + 1) * sz + CUT - 1) / CUT;
    const int sx = ox + (j * sz) / CUT;
    const int ex = ox + ((j + 1) * sz + CUT - 1) / CUT;

    const float* __restrict__ plane = in + bc * (HH * WW);

    float sum = 0.0f;
    for (int y = sy; y < ey; ++y) {
        const float* __restrict__ row = plane + y * WW;
        for (int x = sx; x < ex; ++x) sum += row[x];
    }

    const int cnt = (ey - sy) * (ex - sx);
    out[(size_t)img * PIX + p] = sum * __builtin_amdgcn_rcpf((float)cnt);
}

extern "C" void kernel_launch(void* const* d_in, const int* in_sizes, int n_in,
                              void* d_out, int out_size, void* d_ws, size_t ws_size,
                              hipStream_t stream) {
    const float* in    = (const float*)d_in[0];
    const int*   sizes = (const int*)d_in[1];
    const int*   offx  = (const int*)d_in[2];
    const int*   offy  = (const int*)d_in[3];
    float*       out   = (float*)d_out;

    dim3 grid(PIX / 256, 32 * BC);   // (196, 192)
    make_cutouts_kernel<<<grid, dim3(256), 0, stream>>>(in, sizes, offx, offy, out);
}

// Round 2
// 37.709 us; speedup vs baseline: 1.5031x; 1.5031x over previous
//
#include <hip/hip_runtime.h>

// MakeCutouts: 32 random crops (size in [224,512]) of a [2,3,512,512] fp32
// image, each adaptive-avg-pooled (PyTorch semantics) to 224x224.
// Output: [32*2, 3, 224, 224] fp32.
//
// R1: one block computes all 6 (b,c) planes for its pixel strip — bin math
// amortized 6x, 6 independent loads per window element (MLP), 6x fewer waves.
// Output stores are nontemporal so the 38.5 MB output stream doesn't evict
// the 6.3 MB input from the per-XCD L2s (R0 showed 6.3x read amplification).

constexpr int CUT   = 224;
constexpr int BC    = 6;          // B*C = 2*3
constexpr int HH    = 512;
constexpr int WW    = 512;
constexpr int PIX   = CUT * CUT;  // 50176 = 196 * 256
constexpr int PLANE = HH * WW;

__global__ __launch_bounds__(256) void make_cutouts_kernel(
    const float* __restrict__ in,     // [6, 512, 512] flattened planes
    const int*   __restrict__ sizes,  // [32]
    const int*   __restrict__ offx,   // [32]
    const int*   __restrict__ offy,   // [32]
    float*       __restrict__ out)    // [32, 6, 224, 224] viewed flat
{
    const int p = blockIdx.x * 256 + threadIdx.x;  // pixel index in 224x224
    const int n = blockIdx.y;                      // cutout index (uniform)

    const int i = p / CUT;
    const int j = p - i * CUT;

    const int sz = sizes[n];   // uniform -> scalar loads
    const int oy = offy[n];
    const int ox = offx[n];

    const int sy = (i * sz) / CUT;
    const int ey = ((i + 1) * sz + CUT - 1) / CUT;
    const int sx = (j * sz) / CUT;
    const int ex = ((j + 1) * sz + CUT - 1) / CUT;
    const int dy = ey - sy;    // 1..3
    const int dx = ex - sx;    // 1..3

    const int off = (oy + sy) * WW + (ox + sx);    // element offset in a plane

    float s0 = 0.f, s1 = 0.f, s2 = 0.f, s3 = 0.f, s4 = 0.f, s5 = 0.f;
    for (int y = 0; y < dy; ++y) {
        const int ro = off + y * WW;
        for (int x = 0; x < dx; ++x) {
            const float* __restrict__ q = in + (ro + x);
            s0 += q[0];
            s1 += q[PLANE];
            s2 += q[2 * PLANE];
            s3 += q[3 * PLANE];
            s4 += q[4 * PLANE];
            s5 += q[5 * PLANE];
        }
    }

    const float r = __builtin_amdgcn_rcpf((float)(dy * dx));
    float* o = out + (size_t)n * BC * PIX + p;
    __builtin_nontemporal_store(s0 * r, o);
    __builtin_nontemporal_store(s1 * r, o + PIX);
    __builtin_nontemporal_store(s2 * r, o + 2 * PIX);
    __builtin_nontemporal_store(s3 * r, o + 3 * PIX);
    __builtin_nontemporal_store(s4 * r, o + 4 * PIX);
    __builtin_nontemporal_store(s5 * r, o + 5 * PIX);
}

extern "C" void kernel_launch(void* const* d_in, const int* in_sizes, int n_in,
                              void* d_out, int out_size, void* d_ws, size_t ws_size,
                              hipStream_t stream) {
    const float* in    = (const float*)d_in[0];
    const int*   sizes = (const int*)d_in[1];
    const int*   offx  = (const int*)d_in[2];
    const int*   offy  = (const int*)d_in[3];
    float*       out   = (float*)d_out;

    dim3 grid(PIX / 256, 32);   // (196, 32)
    make_cutouts_kernel<<<grid, dim3(256), 0, stream>>>(in, sizes, offx, offy, out);
}